// Round 1
// baseline (409.523 us; speedup 1.0000x reference)
//
#include <hip/hip_runtime.h>
#include <hip/hip_bf16.h>

#define N_NODES 100000
#define N_EDGES 1600000
#define C 64

__device__ __forceinline__ int lower_bound_i32(const int* __restrict__ a, int lo, int hi, int key) {
    // first index in [lo,hi) with a[i] >= key
    while (lo < hi) {
        int mid = (lo + hi) >> 1;
        if (a[mid] < key) lo = mid + 1; else hi = mid;
    }
    return lo;
}

__global__ __launch_bounds__(256) void graph_conv_mean_kernel(
        const float* __restrict__ x,       // [N_NODES, C]
        const float* __restrict__ w,       // [N_EDGES, C]
        const int*   __restrict__ idxn,    // [N_EDGES]
        const int*   __restrict__ seg,     // [N_EDGES] sorted
        float*       __restrict__ out)     // [N_NODES, C]
{
    const int lane = threadIdx.x & 63;
    const int wave = threadIdx.x >> 6;
    const int node = blockIdx.x * 4 + wave;   // 4 waves per 256-thread block
    if (node >= N_NODES) return;

    // Wave-uniform binary search for this node's contiguous edge range.
    const int lo = lower_bound_i32(seg, 0, N_EDGES, node);
    const int hi = lower_bound_i32(seg, lo, N_EDGES, node + 1);

    float acc = 0.0f;
    for (int e = lo; e < hi; ++e) {
        const int src = idxn[e];                       // wave-uniform, cached
        const float xv = x[(size_t)src * C + lane];    // coalesced 256B, L2/L3-resident
        const float wv = w[(size_t)e   * C + lane];    // coalesced 256B, streaming
        acc = fmaf(xv, wv, acc);
    }

    const int cnt = hi - lo;
    out[(size_t)node * C + lane] = (cnt > 0) ? (acc / (float)cnt) : 0.0f;
}

extern "C" void kernel_launch(void* const* d_in, const int* in_sizes, int n_in,
                              void* d_out, int out_size, void* d_ws, size_t ws_size,
                              hipStream_t stream) {
    const float* x    = (const float*)d_in[0];
    const float* w    = (const float*)d_in[1];
    const int*   idxn = (const int*)d_in[2];
    const int*   seg  = (const int*)d_in[3];
    float*       out  = (float*)d_out;

    const int waves_per_block = 4;                  // 256 threads
    const int grid = (N_NODES + waves_per_block - 1) / waves_per_block;
    graph_conv_mean_kernel<<<grid, 256, 0, stream>>>(x, w, idxn, seg, out);
}

// Round 2
// 123.842 us; speedup vs baseline: 3.3068x; 3.3068x over previous
//
#include <hip/hip_runtime.h>
#include <hip/hip_bf16.h>

#define N_NODES 100000
#define N_EDGES 1600000
#define C 64

// ---------------------------------------------------------------------------
// Pass 1: build CSR row offsets from the sorted seg_ids array.
// offs[n] = lower_bound(seg, n)  for n in [0, N_NODES];  offs[N_NODES] = N_EDGES.
// Edge-parallel boundary marking: thread e covers nodes (seg[e-1], seg[e]].
// Every entry of offs is written exactly once (seg sorted, full coverage).
// ---------------------------------------------------------------------------
__global__ __launch_bounds__(256) void build_offsets_kernel(
        const int* __restrict__ seg, int* __restrict__ offs)
{
    const int e = blockIdx.x * 256 + threadIdx.x;
    if (e >= N_EDGES) return;
    const int s = seg[e];
    const int prev = (e == 0) ? -1 : seg[e - 1];
    for (int n = prev + 1; n <= s; ++n) offs[n] = e;          // first edge with seg >= n
    if (e == N_EDGES - 1) {
        for (int n = s + 1; n <= N_NODES; ++n) offs[n] = N_EDGES;
    }
}

__device__ __forceinline__ int lower_bound_i32(const int* __restrict__ a, int lo, int hi, int key) {
    while (lo < hi) {
        int mid = (lo + hi) >> 1;
        if (a[mid] < key) lo = mid + 1; else hi = mid;
    }
    return lo;
}

// ---------------------------------------------------------------------------
// Main kernel: one 64-lane wave per node, lane = channel.
// Batched idxn loads (one lane-parallel load per <=64 edges) + x4 unrolled
// inner loop with 4 accumulators for memory-level parallelism.
// ---------------------------------------------------------------------------
template <bool USE_OFFS>
__global__ __launch_bounds__(256) void graph_conv_mean_kernel(
        const float* __restrict__ x,       // [N_NODES, C]
        const float* __restrict__ w,       // [N_EDGES, C]
        const int*   __restrict__ idxn,    // [N_EDGES]
        const int*   __restrict__ seg,     // [N_EDGES] sorted (fallback path)
        const int*   __restrict__ offs,    // [N_NODES+1] (fast path)
        float*       __restrict__ out)     // [N_NODES, C]
{
    const int lane = threadIdx.x & 63;
    const int node = (blockIdx.x << 2) + (threadIdx.x >> 6);   // 4 waves / block
    if (node >= N_NODES) return;

    int lo, hi;
    if (USE_OFFS) {
        lo = offs[node];
        hi = offs[node + 1];
    } else {
        lo = lower_bound_i32(seg, 0, N_EDGES, node);
        hi = lower_bound_i32(seg, lo, N_EDGES, node + 1);
    }

    float acc0 = 0.f, acc1 = 0.f, acc2 = 0.f, acc3 = 0.f;
    int e = lo;
    while (e < hi) {
        int n = hi - e; if (n > 64) n = 64;
        int my = 0;
        if (lane < n) my = idxn[e + lane];   // one coalesced load covers the batch
        int j = 0;
        for (; j + 4 <= n; j += 4) {
            const int s0 = __shfl(my, j);
            const int s1 = __shfl(my, j + 1);
            const int s2 = __shfl(my, j + 2);
            const int s3 = __shfl(my, j + 3);
            const float x0 = x[(size_t)s0 * C + lane];
            const float x1 = x[(size_t)s1 * C + lane];
            const float x2 = x[(size_t)s2 * C + lane];
            const float x3 = x[(size_t)s3 * C + lane];
            const float w0 = w[(size_t)(e + j + 0) * C + lane];
            const float w1 = w[(size_t)(e + j + 1) * C + lane];
            const float w2 = w[(size_t)(e + j + 2) * C + lane];
            const float w3 = w[(size_t)(e + j + 3) * C + lane];
            acc0 = fmaf(x0, w0, acc0);
            acc1 = fmaf(x1, w1, acc1);
            acc2 = fmaf(x2, w2, acc2);
            acc3 = fmaf(x3, w3, acc3);
        }
        for (; j < n; ++j) {
            const int s = __shfl(my, j);
            acc0 = fmaf(x[(size_t)s * C + lane], w[(size_t)(e + j) * C + lane], acc0);
        }
        e += n;
    }

    const float acc = (acc0 + acc1) + (acc2 + acc3);
    const int cnt = hi - lo;
    out[(size_t)node * C + lane] = (cnt > 0) ? (acc / (float)cnt) : 0.0f;
}

extern "C" void kernel_launch(void* const* d_in, const int* in_sizes, int n_in,
                              void* d_out, int out_size, void* d_ws, size_t ws_size,
                              hipStream_t stream) {
    const float* x    = (const float*)d_in[0];
    const float* w    = (const float*)d_in[1];
    const int*   idxn = (const int*)d_in[2];
    const int*   seg  = (const int*)d_in[3];
    float*       out  = (float*)d_out;

    const int grid_main = (N_NODES + 3) / 4;                    // 4 waves per block
    const size_t offs_bytes = (size_t)(N_NODES + 1) * sizeof(int);

    if (ws_size >= offs_bytes) {
        int* offs = (int*)d_ws;
        build_offsets_kernel<<<(N_EDGES + 255) / 256, 256, 0, stream>>>(seg, offs);
        graph_conv_mean_kernel<true><<<grid_main, 256, 0, stream>>>(x, w, idxn, seg, offs, out);
    } else {
        graph_conv_mean_kernel<false><<<grid_main, 256, 0, stream>>>(x, w, idxn, seg, (const int*)nullptr, out);
    }
}

// Round 3
// 123.726 us; speedup vs baseline: 3.3099x; 1.0009x over previous
//
#include <hip/hip_runtime.h>
#include <hip/hip_bf16.h>

#define N_NODES 100000
#define N_EDGES 1600000
#define C 64

// ---------------------------------------------------------------------------
// Pass 1: CSR row offsets from sorted seg_ids.
// offs[n] = first edge with seg >= n; offs[N_NODES] = N_EDGES.
// One seg load per thread; predecessor via __shfl_up (lane 0 reloads).
// ---------------------------------------------------------------------------
__global__ __launch_bounds__(256) void build_offsets_kernel(
        const int* __restrict__ seg, int* __restrict__ offs)
{
    const int e = blockIdx.x * 256 + threadIdx.x;
    if (e >= N_EDGES) return;                      // N_EDGES % 256 == 0: no divergence
    const int s = seg[e];
    int prev = __shfl_up(s, 1);
    if ((threadIdx.x & 63) == 0) prev = (e == 0) ? -1 : seg[e - 1];
    for (int n = prev + 1; n <= s; ++n) offs[n] = e;
    if (e == N_EDGES - 1)
        for (int n = s + 1; n <= N_NODES; ++n) offs[n] = N_EDGES;
}

// ---------------------------------------------------------------------------
// Main kernel: one wave per node. Lane l = (edge-chunk l>>4, channels (l&15)*4).
// Each load instruction covers 4 edges x 16B/lane = 1KB. 16-edge main body
// keeps 8 float4 loads in flight. Final cross-chunk reduce: shfl_xor 16,32.
// ---------------------------------------------------------------------------
__global__ __launch_bounds__(256) void graph_conv_mean_kernel(
        const float* __restrict__ x,       // [N_NODES, C]
        const float* __restrict__ w,       // [N_EDGES, C]
        const int*   __restrict__ idxn,    // [N_EDGES]
        const int*   __restrict__ offs,    // [N_NODES+1]
        float*       __restrict__ out)     // [N_NODES, C]
{
    const int lane = threadIdx.x & 63;
    const int node = (blockIdx.x << 2) + (threadIdx.x >> 6);   // 4 waves / block
    if (node >= N_NODES) return;

    const int lo = offs[node];
    const int hi = offs[node + 1];
    const int grp = lane >> 4;          // which edge within a 4-edge chunk
    const int ch4 = (lane & 15) << 2;   // channel base (float4)

    float4 acc = make_float4(0.f, 0.f, 0.f, 0.f);

    int e = lo;
    while (e < hi) {
        int n = hi - e; if (n > 64) n = 64;
        const int my = (lane < n) ? idxn[e + lane] : 0;   // one coalesced batch load
        int j = 0;

        // 16-edge body: 4 shfls, 8 x float4 loads in flight, 32 FMAs
        for (; j + 16 <= n; j += 16) {
            const int e0 = j + grp, e1 = j + 4 + grp, e2 = j + 8 + grp, e3 = j + 12 + grp;
            const int s0 = __shfl(my, e0), s1 = __shfl(my, e1);
            const int s2 = __shfl(my, e2), s3 = __shfl(my, e3);
            const float4 xa = *(const float4*)(x + (size_t)s0 * C + ch4);
            const float4 wa = *(const float4*)(w + (size_t)(e + e0) * C + ch4);
            const float4 xb = *(const float4*)(x + (size_t)s1 * C + ch4);
            const float4 wb = *(const float4*)(w + (size_t)(e + e1) * C + ch4);
            const float4 xc = *(const float4*)(x + (size_t)s2 * C + ch4);
            const float4 wc = *(const float4*)(w + (size_t)(e + e2) * C + ch4);
            const float4 xd = *(const float4*)(x + (size_t)s3 * C + ch4);
            const float4 wd = *(const float4*)(w + (size_t)(e + e3) * C + ch4);
            acc.x = fmaf(xa.x, wa.x, acc.x); acc.y = fmaf(xa.y, wa.y, acc.y);
            acc.z = fmaf(xa.z, wa.z, acc.z); acc.w = fmaf(xa.w, wa.w, acc.w);
            acc.x = fmaf(xb.x, wb.x, acc.x); acc.y = fmaf(xb.y, wb.y, acc.y);
            acc.z = fmaf(xb.z, wb.z, acc.z); acc.w = fmaf(xb.w, wb.w, acc.w);
            acc.x = fmaf(xc.x, wc.x, acc.x); acc.y = fmaf(xc.y, wc.y, acc.y);
            acc.z = fmaf(xc.z, wc.z, acc.z); acc.w = fmaf(xc.w, wc.w, acc.w);
            acc.x = fmaf(xd.x, wd.x, acc.x); acc.y = fmaf(xd.y, wd.y, acc.y);
            acc.z = fmaf(xd.z, wd.z, acc.z); acc.w = fmaf(xd.w, wd.w, acc.w);
        }
        // 8-edge body
        for (; j + 8 <= n; j += 8) {
            const int e0 = j + grp, e1 = j + 4 + grp;
            const int s0 = __shfl(my, e0), s1 = __shfl(my, e1);
            const float4 xa = *(const float4*)(x + (size_t)s0 * C + ch4);
            const float4 wa = *(const float4*)(w + (size_t)(e + e0) * C + ch4);
            const float4 xb = *(const float4*)(x + (size_t)s1 * C + ch4);
            const float4 wb = *(const float4*)(w + (size_t)(e + e1) * C + ch4);
            acc.x = fmaf(xa.x, wa.x, acc.x); acc.y = fmaf(xa.y, wa.y, acc.y);
            acc.z = fmaf(xa.z, wa.z, acc.z); acc.w = fmaf(xa.w, wa.w, acc.w);
            acc.x = fmaf(xb.x, wb.x, acc.x); acc.y = fmaf(xb.y, wb.y, acc.y);
            acc.z = fmaf(xb.z, wb.z, acc.z); acc.w = fmaf(xb.w, wb.w, acc.w);
        }
        // masked 4-edge tail
        for (; j < n; j += 4) {
            const int eo = j + grp;
            const bool valid = eo < n;
            const int s = __shfl(my, valid ? eo : j);
            if (valid) {
                const float4 xv = *(const float4*)(x + (size_t)s * C + ch4);
                const float4 wv = *(const float4*)(w + (size_t)(e + eo) * C + ch4);
                acc.x = fmaf(xv.x, wv.x, acc.x); acc.y = fmaf(xv.y, wv.y, acc.y);
                acc.z = fmaf(xv.z, wv.z, acc.z); acc.w = fmaf(xv.w, wv.w, acc.w);
            }
        }
        e += n;
    }

    // Sum the 4 edge-chunk groups (lanes l, l^16, l^32, l^48 share a channel set)
    acc.x += __shfl_xor(acc.x, 16); acc.y += __shfl_xor(acc.y, 16);
    acc.z += __shfl_xor(acc.z, 16); acc.w += __shfl_xor(acc.w, 16);
    acc.x += __shfl_xor(acc.x, 32); acc.y += __shfl_xor(acc.y, 32);
    acc.z += __shfl_xor(acc.z, 32); acc.w += __shfl_xor(acc.w, 32);

    if (lane < 16) {
        const int cnt = hi - lo;
        float4 r = make_float4(0.f, 0.f, 0.f, 0.f);
        if (cnt > 0) {
            const float inv = 1.0f / (float)cnt;
            r = make_float4(acc.x * inv, acc.y * inv, acc.z * inv, acc.w * inv);
        }
        *(float4*)(out + (size_t)node * C + ch4) = r;
    }
}

extern "C" void kernel_launch(void* const* d_in, const int* in_sizes, int n_in,
                              void* d_out, int out_size, void* d_ws, size_t ws_size,
                              hipStream_t stream) {
    const float* x    = (const float*)d_in[0];
    const float* w    = (const float*)d_in[1];
    const int*   idxn = (const int*)d_in[2];
    const int*   seg  = (const int*)d_in[3];
    float*       out  = (float*)d_out;

    int* offs = (int*)d_ws;   // N_NODES+1 ints = 400 KB, ws guaranteed large enough

    build_offsets_kernel<<<(N_EDGES + 255) / 256, 256, 0, stream>>>(seg, offs);
    const int grid_main = (N_NODES + 3) / 4;
    graph_conv_mean_kernel<<<grid_main, 256, 0, stream>>>(x, w, idxn, offs, out);
}

// Round 4
// 106.776 us; speedup vs baseline: 3.8354x; 1.1587x over previous
//
#include <hip/hip_runtime.h>
#include <hip/hip_bf16.h>

#define N_NODES 100000
#define N_EDGES 1600000
#define C 64

// d_ws layout:
//   [0, 400004)            : offs (N_NODES+1 ints)
//   [1 MiB, 1 MiB+12.8 MB) : x_bf16 shadow [N_NODES][C] ushort
#define WS_XB_OFFSET (1u << 20)

__device__ __forceinline__ unsigned short f2bf_rne(float f) {
    unsigned u = __float_as_uint(f);
    unsigned r = u + 0x7FFFu + ((u >> 16) & 1u);
    return (unsigned short)(r >> 16);
}
__device__ __forceinline__ float bf2f(unsigned short b) {
    return __uint_as_float((unsigned)b << 16);
}

// ---------------------------------------------------------------------------
// Pass 1a: CSR row offsets from sorted seg_ids.
// ---------------------------------------------------------------------------
__global__ __launch_bounds__(256) void build_offsets_kernel(
        const int* __restrict__ seg, int* __restrict__ offs)
{
    const int e = blockIdx.x * 256 + threadIdx.x;
    if (e >= N_EDGES) return;                      // N_EDGES % 256 == 0
    const int s = seg[e];
    int prev = __shfl_up(s, 1);
    if ((threadIdx.x & 63) == 0) prev = (e == 0) ? -1 : seg[e - 1];
    for (int n = prev + 1; n <= s; ++n) offs[n] = e;
    if (e == N_EDGES - 1)
        for (int n = s + 1; n <= N_NODES; ++n) offs[n] = N_EDGES;
}

// ---------------------------------------------------------------------------
// Pass 1b: x (fp32) -> x_bf16 shadow. Halves the gathered working set so the
// random per-edge x-row fetch moves from L3-fabric traffic toward L2 hits.
// ---------------------------------------------------------------------------
__global__ __launch_bounds__(256) void convert_x_bf16_kernel(
        const float* __restrict__ x, ushort* __restrict__ xb)
{
    const int i = blockIdx.x * 256 + threadIdx.x;      // float4 index
    const int total4 = N_NODES * C / 4;                // 1.6M
    if (i >= total4) return;
    const float4 v = ((const float4*)x)[i];
    ushort4 o;
    o.x = f2bf_rne(v.x); o.y = f2bf_rne(v.y);
    o.z = f2bf_rne(v.z); o.w = f2bf_rne(v.w);
    ((ushort4*)xb)[i] = o;
}

// ---------------------------------------------------------------------------
// Main kernel: one wave per node. Lane l = (edge-chunk l>>4, channels (l&15)*4).
// w: float4 (16B/lane, streaming).  x: bf16 ushort4 (8B/lane, gathered).
// ---------------------------------------------------------------------------
__global__ __launch_bounds__(256) void graph_conv_mean_kernel(
        const ushort* __restrict__ xb,     // [N_NODES, C] bf16
        const float*  __restrict__ w,      // [N_EDGES, C]
        const int*    __restrict__ idxn,   // [N_EDGES]
        const int*    __restrict__ offs,   // [N_NODES+1]
        float*        __restrict__ out)    // [N_NODES, C]
{
    const int lane = threadIdx.x & 63;
    const int node = (blockIdx.x << 2) + (threadIdx.x >> 6);   // 4 waves / block
    if (node >= N_NODES) return;

    const int lo = offs[node];
    const int hi = offs[node + 1];
    const int grp = lane >> 4;          // edge within a 4-edge chunk
    const int ch4 = (lane & 15) << 2;   // channel base (x4)

    float4 acc = make_float4(0.f, 0.f, 0.f, 0.f);

    int e = lo;
    while (e < hi) {
        int n = hi - e; if (n > 64) n = 64;
        const int my = (lane < n) ? idxn[e + lane] : 0;
        int j = 0;

        // 16-edge body: 4 shfls, 4 ushort4 + 4 float4 loads in flight
        for (; j + 16 <= n; j += 16) {
            const int e0 = j + grp, e1 = j + 4 + grp, e2 = j + 8 + grp, e3 = j + 12 + grp;
            const int s0 = __shfl(my, e0), s1 = __shfl(my, e1);
            const int s2 = __shfl(my, e2), s3 = __shfl(my, e3);
            const ushort4 xa = *(const ushort4*)(xb + (size_t)s0 * C + ch4);
            const float4  wa = *(const float4*)(w + (size_t)(e + e0) * C + ch4);
            const ushort4 xbv = *(const ushort4*)(xb + (size_t)s1 * C + ch4);
            const float4  wb = *(const float4*)(w + (size_t)(e + e1) * C + ch4);
            const ushort4 xc = *(const ushort4*)(xb + (size_t)s2 * C + ch4);
            const float4  wc = *(const float4*)(w + (size_t)(e + e2) * C + ch4);
            const ushort4 xd = *(const ushort4*)(xb + (size_t)s3 * C + ch4);
            const float4  wd = *(const float4*)(w + (size_t)(e + e3) * C + ch4);
            acc.x = fmaf(bf2f(xa.x), wa.x, acc.x); acc.y = fmaf(bf2f(xa.y), wa.y, acc.y);
            acc.z = fmaf(bf2f(xa.z), wa.z, acc.z); acc.w = fmaf(bf2f(xa.w), wa.w, acc.w);
            acc.x = fmaf(bf2f(xbv.x), wb.x, acc.x); acc.y = fmaf(bf2f(xbv.y), wb.y, acc.y);
            acc.z = fmaf(bf2f(xbv.z), wb.z, acc.z); acc.w = fmaf(bf2f(xbv.w), wb.w, acc.w);
            acc.x = fmaf(bf2f(xc.x), wc.x, acc.x); acc.y = fmaf(bf2f(xc.y), wc.y, acc.y);
            acc.z = fmaf(bf2f(xc.z), wc.z, acc.z); acc.w = fmaf(bf2f(xc.w), wc.w, acc.w);
            acc.x = fmaf(bf2f(xd.x), wd.x, acc.x); acc.y = fmaf(bf2f(xd.y), wd.y, acc.y);
            acc.z = fmaf(bf2f(xd.z), wd.z, acc.z); acc.w = fmaf(bf2f(xd.w), wd.w, acc.w);
        }
        // 8-edge body
        for (; j + 8 <= n; j += 8) {
            const int e0 = j + grp, e1 = j + 4 + grp;
            const int s0 = __shfl(my, e0), s1 = __shfl(my, e1);
            const ushort4 xa = *(const ushort4*)(xb + (size_t)s0 * C + ch4);
            const float4  wa = *(const float4*)(w + (size_t)(e + e0) * C + ch4);
            const ushort4 xbv = *(const ushort4*)(xb + (size_t)s1 * C + ch4);
            const float4  wb = *(const float4*)(w + (size_t)(e + e1) * C + ch4);
            acc.x = fmaf(bf2f(xa.x), wa.x, acc.x); acc.y = fmaf(bf2f(xa.y), wa.y, acc.y);
            acc.z = fmaf(bf2f(xa.z), wa.z, acc.z); acc.w = fmaf(bf2f(xa.w), wa.w, acc.w);
            acc.x = fmaf(bf2f(xbv.x), wb.x, acc.x); acc.y = fmaf(bf2f(xbv.y), wb.y, acc.y);
            acc.z = fmaf(bf2f(xbv.z), wb.z, acc.z); acc.w = fmaf(bf2f(xbv.w), wb.w, acc.w);
        }
        // masked 4-edge tail
        for (; j < n; j += 4) {
            const int eo = j + grp;
            const bool valid = eo < n;
            const int s = __shfl(my, valid ? eo : j);
            if (valid) {
                const ushort4 xv = *(const ushort4*)(xb + (size_t)s * C + ch4);
                const float4  wv = *(const float4*)(w + (size_t)(e + eo) * C + ch4);
                acc.x = fmaf(bf2f(xv.x), wv.x, acc.x); acc.y = fmaf(bf2f(xv.y), wv.y, acc.y);
                acc.z = fmaf(bf2f(xv.z), wv.z, acc.z); acc.w = fmaf(bf2f(xv.w), wv.w, acc.w);
            }
        }
        e += n;
    }

    // Fold the 4 edge-chunk groups
    acc.x += __shfl_xor(acc.x, 16); acc.y += __shfl_xor(acc.y, 16);
    acc.z += __shfl_xor(acc.z, 16); acc.w += __shfl_xor(acc.w, 16);
    acc.x += __shfl_xor(acc.x, 32); acc.y += __shfl_xor(acc.y, 32);
    acc.z += __shfl_xor(acc.z, 32); acc.w += __shfl_xor(acc.w, 32);

    if (lane < 16) {
        const int cnt = hi - lo;
        float4 r = make_float4(0.f, 0.f, 0.f, 0.f);
        if (cnt > 0) {
            const float inv = 1.0f / (float)cnt;
            r = make_float4(acc.x * inv, acc.y * inv, acc.z * inv, acc.w * inv);
        }
        *(float4*)(out + (size_t)node * C + ch4) = r;
    }
}

extern "C" void kernel_launch(void* const* d_in, const int* in_sizes, int n_in,
                              void* d_out, int out_size, void* d_ws, size_t ws_size,
                              hipStream_t stream) {
    const float* x    = (const float*)d_in[0];
    const float* w    = (const float*)d_in[1];
    const int*   idxn = (const int*)d_in[2];
    const int*   seg  = (const int*)d_in[3];
    float*       out  = (float*)d_out;

    int*    offs = (int*)d_ws;
    ushort* xb   = (ushort*)((char*)d_ws + WS_XB_OFFSET);

    build_offsets_kernel<<<(N_EDGES + 255) / 256, 256, 0, stream>>>(seg, offs);
    convert_x_bf16_kernel<<<(N_NODES * C / 4 + 255) / 256, 256, 0, stream>>>(x, xb);
    const int grid_main = (N_NODES + 3) / 4;
    graph_conv_mean_kernel<<<grid_main, 256, 0, stream>>>(xb, w, idxn, offs, out);
}

// Round 5
// 104.086 us; speedup vs baseline: 3.9345x; 1.0258x over previous
//
#include <hip/hip_runtime.h>
#include <hip/hip_bf16.h>

#define N_NODES 100000
#define N_EDGES 1600000
#define C 64

// d_ws layout:
//   [0, 400004)            : offs (N_NODES+1 ints)
//   [1 MiB, 1 MiB+12.8 MB) : x_bf16 shadow [N_NODES][C] ushort
#define WS_XB_OFFSET (1u << 20)

typedef __attribute__((ext_vector_type(4))) float f32x4;
typedef __attribute__((ext_vector_type(4))) unsigned short u16x4;

__device__ __forceinline__ unsigned short f2bf_rne(float f) {
    unsigned u = __float_as_uint(f);
    unsigned r = u + 0x7FFFu + ((u >> 16) & 1u);
    return (unsigned short)(r >> 16);
}
__device__ __forceinline__ float bf2f(unsigned short b) {
    return __uint_as_float((unsigned)b << 16);
}

// ---------------------------------------------------------------------------
// Fused pre-pass (one dispatch, two block ranges):
//   blocks [0, CONV_BLOCKS)        : x fp32 -> bf16 shadow (nt reads of x)
//   blocks [CONV_BLOCKS, +OFF_BLK) : CSR offsets from sorted seg (nt reads)
// ---------------------------------------------------------------------------
#define CONV_BLOCKS (N_NODES * C / 4 / 256)   // 6250
#define OFF_BLOCKS  (N_EDGES / 256)           // 6250

__global__ __launch_bounds__(256) void prepass_kernel(
        const int* __restrict__ seg, int* __restrict__ offs,
        const float* __restrict__ x, ushort* __restrict__ xb)
{
    if ((int)blockIdx.x < CONV_BLOCKS) {
        const int i = blockIdx.x * 256 + threadIdx.x;          // float4 index
        const f32x4 v = __builtin_nontemporal_load((const f32x4*)x + i);
        u16x4 o;
        o.x = f2bf_rne(v.x); o.y = f2bf_rne(v.y);
        o.z = f2bf_rne(v.z); o.w = f2bf_rne(v.w);
        ((u16x4*)xb)[i] = o;                                   // cached: re-read by gather
    } else {
        const int e = (blockIdx.x - CONV_BLOCKS) * 256 + threadIdx.x;
        const int s = __builtin_nontemporal_load(seg + e);
        int prev = __shfl_up(s, 1);
        if ((threadIdx.x & 63) == 0) prev = (e == 0) ? -1 : seg[e - 1];
        for (int n = prev + 1; n <= s; ++n) offs[n] = e;
        if (e == N_EDGES - 1)
            for (int n = s + 1; n <= N_NODES; ++n) offs[n] = N_EDGES;
    }
}

// ---------------------------------------------------------------------------
// Main kernel: one wave per node. Lane l = (edge-chunk l>>4, channels (l&15)*4).
// w: nt float4 (single-use stream — don't evict xb from L2/L3).
// xb: cached ushort4 gather.  out: nt store (write-once).
// ---------------------------------------------------------------------------
__global__ __launch_bounds__(256) void graph_conv_mean_kernel(
        const ushort* __restrict__ xb,     // [N_NODES, C] bf16
        const float*  __restrict__ w,      // [N_EDGES, C]
        const int*    __restrict__ idxn,   // [N_EDGES]
        const int*    __restrict__ offs,   // [N_NODES+1]
        float*        __restrict__ out)    // [N_NODES, C]
{
    const int lane = threadIdx.x & 63;
    const int node = (blockIdx.x << 2) + (threadIdx.x >> 6);   // 4 waves / block
    if (node >= N_NODES) return;

    const int lo = offs[node];
    const int hi = offs[node + 1];
    const int grp = lane >> 4;          // edge within a 4-edge chunk
    const int ch4 = (lane & 15) << 2;   // channel base (x4)

    float4 acc = make_float4(0.f, 0.f, 0.f, 0.f);

    int e = lo;
    while (e < hi) {
        int n = hi - e; if (n > 64) n = 64;
        const int my = (lane < n) ? __builtin_nontemporal_load(idxn + e + lane) : 0;
        int j = 0;

        // 16-edge body: 4 shfls, 4 ushort4 + 4 nt float4 loads in flight
        for (; j + 16 <= n; j += 16) {
            const int e0 = j + grp, e1 = j + 4 + grp, e2 = j + 8 + grp, e3 = j + 12 + grp;
            const int s0 = __shfl(my, e0), s1 = __shfl(my, e1);
            const int s2 = __shfl(my, e2), s3 = __shfl(my, e3);
            const u16x4 xa = *(const u16x4*)(xb + (size_t)s0 * C + ch4);
            const f32x4 wa = __builtin_nontemporal_load((const f32x4*)(w + (size_t)(e + e0) * C + ch4));
            const u16x4 xv1 = *(const u16x4*)(xb + (size_t)s1 * C + ch4);
            const f32x4 wb = __builtin_nontemporal_load((const f32x4*)(w + (size_t)(e + e1) * C + ch4));
            const u16x4 xc = *(const u16x4*)(xb + (size_t)s2 * C + ch4);
            const f32x4 wc = __builtin_nontemporal_load((const f32x4*)(w + (size_t)(e + e2) * C + ch4));
            const u16x4 xd = *(const u16x4*)(xb + (size_t)s3 * C + ch4);
            const f32x4 wd = __builtin_nontemporal_load((const f32x4*)(w + (size_t)(e + e3) * C + ch4));
            acc.x = fmaf(bf2f(xa.x), wa.x, acc.x); acc.y = fmaf(bf2f(xa.y), wa.y, acc.y);
            acc.z = fmaf(bf2f(xa.z), wa.z, acc.z); acc.w = fmaf(bf2f(xa.w), wa.w, acc.w);
            acc.x = fmaf(bf2f(xv1.x), wb.x, acc.x); acc.y = fmaf(bf2f(xv1.y), wb.y, acc.y);
            acc.z = fmaf(bf2f(xv1.z), wb.z, acc.z); acc.w = fmaf(bf2f(xv1.w), wb.w, acc.w);
            acc.x = fmaf(bf2f(xc.x), wc.x, acc.x); acc.y = fmaf(bf2f(xc.y), wc.y, acc.y);
            acc.z = fmaf(bf2f(xc.z), wc.z, acc.z); acc.w = fmaf(bf2f(xc.w), wc.w, acc.w);
            acc.x = fmaf(bf2f(xd.x), wd.x, acc.x); acc.y = fmaf(bf2f(xd.y), wd.y, acc.y);
            acc.z = fmaf(bf2f(xd.z), wd.z, acc.z); acc.w = fmaf(bf2f(xd.w), wd.w, acc.w);
        }
        // 8-edge body
        for (; j + 8 <= n; j += 8) {
            const int e0 = j + grp, e1 = j + 4 + grp;
            const int s0 = __shfl(my, e0), s1 = __shfl(my, e1);
            const u16x4 xa = *(const u16x4*)(xb + (size_t)s0 * C + ch4);
            const f32x4 wa = __builtin_nontemporal_load((const f32x4*)(w + (size_t)(e + e0) * C + ch4));
            const u16x4 xv1 = *(const u16x4*)(xb + (size_t)s1 * C + ch4);
            const f32x4 wb = __builtin_nontemporal_load((const f32x4*)(w + (size_t)(e + e1) * C + ch4));
            acc.x = fmaf(bf2f(xa.x), wa.x, acc.x); acc.y = fmaf(bf2f(xa.y), wa.y, acc.y);
            acc.z = fmaf(bf2f(xa.z), wa.z, acc.z); acc.w = fmaf(bf2f(xa.w), wa.w, acc.w);
            acc.x = fmaf(bf2f(xv1.x), wb.x, acc.x); acc.y = fmaf(bf2f(xv1.y), wb.y, acc.y);
            acc.z = fmaf(bf2f(xv1.z), wb.z, acc.z); acc.w = fmaf(bf2f(xv1.w), wb.w, acc.w);
        }
        // masked 4-edge tail
        for (; j < n; j += 4) {
            const int eo = j + grp;
            const bool valid = eo < n;
            const int s = __shfl(my, valid ? eo : j);
            if (valid) {
                const u16x4 xv = *(const u16x4*)(xb + (size_t)s * C + ch4);
                const f32x4 wv = __builtin_nontemporal_load((const f32x4*)(w + (size_t)(e + eo) * C + ch4));
                acc.x = fmaf(bf2f(xv.x), wv.x, acc.x); acc.y = fmaf(bf2f(xv.y), wv.y, acc.y);
                acc.z = fmaf(bf2f(xv.z), wv.z, acc.z); acc.w = fmaf(bf2f(xv.w), wv.w, acc.w);
            }
        }
        e += n;
    }

    // Fold the 4 edge-chunk groups
    acc.x += __shfl_xor(acc.x, 16); acc.y += __shfl_xor(acc.y, 16);
    acc.z += __shfl_xor(acc.z, 16); acc.w += __shfl_xor(acc.w, 16);
    acc.x += __shfl_xor(acc.x, 32); acc.y += __shfl_xor(acc.y, 32);
    acc.z += __shfl_xor(acc.z, 32); acc.w += __shfl_xor(acc.w, 32);

    if (lane < 16) {
        const int cnt = hi - lo;
        f32x4 r = (f32x4)(0.f);
        if (cnt > 0) {
            const float inv = 1.0f / (float)cnt;
            r.x = acc.x * inv; r.y = acc.y * inv; r.z = acc.z * inv; r.w = acc.w * inv;
        }
        __builtin_nontemporal_store(r, (f32x4*)(out + (size_t)node * C + ch4));
    }
}

extern "C" void kernel_launch(void* const* d_in, const int* in_sizes, int n_in,
                              void* d_out, int out_size, void* d_ws, size_t ws_size,
                              hipStream_t stream) {
    const float* x    = (const float*)d_in[0];
    const float* w    = (const float*)d_in[1];
    const int*   idxn = (const int*)d_in[2];
    const int*   seg  = (const int*)d_in[3];
    float*       out  = (float*)d_out;

    int*    offs = (int*)d_ws;
    ushort* xb   = (ushort*)((char*)d_ws + WS_XB_OFFSET);

    prepass_kernel<<<CONV_BLOCKS + OFF_BLOCKS, 256, 0, stream>>>(seg, offs, x, xb);
    const int grid_main = (N_NODES + 3) / 4;
    graph_conv_mean_kernel<<<grid_main, 256, 0, stream>>>(xb, w, idxn, offs, out);
}